// Round 10
// baseline (533.925 us; speedup 1.0000x reference)
//
#include <hip/hip_runtime.h>

#define B_  16
#define T_  2048
#define L_  128
#define H_  512
#define F_  1024
#define EPS 1e-5f

#define SS   (512 * 512)         // one 512x512 matrix (elements)
#define GP2  132                 // 128 + 4 LDS pad
#define GSM2 (32 * GP2 * 2)      // 8448 floats = 33792 B

// ---------------------------------------------------------------------------
// g128: 128x128 tile, BK=32, TM=TN=8, 256 threads. VALU-balanced (1 B/FMA).
// amode: 0 dense A (lda, nsA-slab sum); 1 Wc ([We;be], lda=256);
//        3 U x-gather (row=lag*16+b -> x[b][T-1-lag], +bc epilogue);
//        4 L1 combine A-side (row r: j=r>>4,b=r&15; seg=gk>>9 ->
//          U[(16j+seg+1)*16+b][gk&511]; kc==0 epilogue += U[256j+b]);
//        8 copy Amat into slot0 slab0, zero slabs1-3; 9 slab-reduce.
// bmode: 0 linear (B+gk*512+c, nsB slabs ssB); 1 slotted (slot=gk>>9, 4-slab)
// C slab layout: C + prod*pStrC + kc*M*512 + r*512 + c  (ldc=512 always)
// ---------------------------------------------------------------------------
struct GJob {
    const float* A; const float* Aaux; const float* B; float* C;
    int M, lda, kLen, nbx, nrt, nkc, nprod;
    int amode, bmode, nsA, ssA, nsB, ssB;
    long pStrB, pStrC;
};

__device__ __forceinline__ float4 gldA(const GJob& j, int gr, int gk) {
    if (j.amode == 1) {
        if (gr < 128)  return *(const float4*)(j.A + (long)gr * j.lda + gk);
        if (gr == 128) return *(const float4*)(j.Aaux + gk);
        return make_float4(0.f, 0.f, 0.f, 0.f);
    }
    if (j.amode == 3) {
        int b = gr & 15, lag = gr >> 4;
        return *(const float4*)(j.A + ((long)b * T_ + (T_ - 1 - lag)) * L_ + gk);
    }
    if (j.amode == 4) {
        int j4 = gr >> 4, b = gr & 15, seg = gk >> 9;
        return *(const float4*)(j.A + (long)((16 * j4 + seg + 1) * 16 + b) * 512 +
                                (gk & 511));
    }
    if (gr >= j.M) return make_float4(0.f, 0.f, 0.f, 0.f);
    const float* p = j.A + (long)gr * j.lda + gk;
    float4 s = *(const float4*)p;
    for (int q = 1; q < j.nsA; ++q) {
        float4 t = *(const float4*)(p + (long)q * j.ssA);
        s.x += t.x; s.y += t.y; s.z += t.z; s.w += t.w;
    }
    return s;
}

__device__ __forceinline__ float4 gldB(const GJob& j, const float* Bp,
                                       int gk, int c) {
    if (j.bmode == 1) {
        int slot = gk >> 9;
        const float* p = Bp + (long)slot * 4 * SS + (long)(gk & 511) * 512 + c;
        float4 s = *(const float4*)p;
#pragma unroll
        for (int q = 1; q < 4; ++q) {
            float4 t = *(const float4*)(p + (long)q * SS);
            s.x += t.x; s.y += t.y; s.z += t.z; s.w += t.w;
        }
        return s;
    }
    const float* p = Bp + (long)gk * 512 + c;
    float4 s = *(const float4*)p;
    for (int q = 1; q < j.nsB; ++q) {
        float4 t = *(const float4*)(p + (long)q * j.ssB);
        s.x += t.x; s.y += t.y; s.z += t.z; s.w += t.w;
    }
    return s;
}

__device__ __forceinline__ void g128run(float* sm, const GJob& j, int rel) {
    float* As = sm;                 // [32][132] As[k][m]
    float* Bs = sm + 32 * GP2;      // [32][132] Bs[k][n]
    const int tid = threadIdx.x, tx = tid & 15, ty = tid >> 4;
    int bx = rel % j.nbx;
    int r  = rel / j.nbx;
    int by = r % j.nrt;  r /= j.nrt;
    int kc = r % j.nkc;
    int prod = r / j.nkc;
    const float* Bp = j.B + (long)prod * j.pStrB;
    float* Cp = j.C + (long)prod * j.pStrC;
    const int row0 = by * 128, col0 = bx * 128, kOff = kc * j.kLen;

    float4 pa[4], pb[4];
#pragma unroll
    for (int t = 0; t < 4; ++t) {
        int f = tid + t * 256;
        pa[t] = gldA(j, row0 + (f >> 3), kOff + (f & 7) * 4);
        pb[t] = gldB(j, Bp, kOff + (f >> 5), col0 + (f & 31) * 4);
    }
    float acc[8][8] = {};
    for (int k0 = 0; k0 < j.kLen; k0 += 32) {
        __syncthreads();
#pragma unroll
        for (int t = 0; t < 4; ++t) {
            int f = tid + t * 256;
            int ar = f >> 3, ak = (f & 7) * 4;
            As[(ak + 0) * GP2 + ar] = pa[t].x;
            As[(ak + 1) * GP2 + ar] = pa[t].y;
            As[(ak + 2) * GP2 + ar] = pa[t].z;
            As[(ak + 3) * GP2 + ar] = pa[t].w;
            *(float4*)&Bs[(f >> 5) * GP2 + (f & 31) * 4] = pb[t];
        }
        __syncthreads();
        int kn = k0 + 32;
        if (kn < j.kLen) {
#pragma unroll
            for (int t = 0; t < 4; ++t) {
                int f = tid + t * 256;
                pa[t] = gldA(j, row0 + (f >> 3), kOff + kn + (f & 7) * 4);
                pb[t] = gldB(j, Bp, kOff + kn + (f >> 5), col0 + (f & 31) * 4);
            }
        }
#pragma unroll
        for (int kk = 0; kk < 32; ++kk) {
            float av[8], bv[8];
            *(float4*)&av[0] = *(float4*)&As[kk * GP2 + ty * 8];
            *(float4*)&av[4] = *(float4*)&As[kk * GP2 + ty * 8 + 4];
            *(float4*)&bv[0] = *(float4*)&Bs[kk * GP2 + tx * 8];
            *(float4*)&bv[4] = *(float4*)&Bs[kk * GP2 + tx * 8 + 4];
#pragma unroll
            for (int i = 0; i < 8; ++i)
#pragma unroll
                for (int jj = 0; jj < 8; ++jj)
                    acc[i][jj] = fmaf(av[i], bv[jj], acc[i][jj]);
        }
    }
    long coff = (long)kc * j.M * 512;
#pragma unroll
    for (int i = 0; i < 8; ++i) {
        int rr = row0 + ty * 8 + i;
        if (rr >= j.M) continue;
        int c = col0 + tx * 8;
        float4 v0 = make_float4(acc[i][0], acc[i][1], acc[i][2], acc[i][3]);
        float4 v1 = make_float4(acc[i][4], acc[i][5], acc[i][6], acc[i][7]);
        if (j.amode == 3) {            // += bc (sum of Wc slab row 128)
            for (int q = 0; q < 2; ++q) {
                float4 a0 = *(const float4*)(j.Aaux + (long)q * j.ssA + c);
                float4 a1 = *(const float4*)(j.Aaux + (long)q * j.ssA + c + 4);
                v0.x += a0.x; v0.y += a0.y; v0.z += a0.z; v0.w += a0.w;
                v1.x += a1.x; v1.y += a1.y; v1.z += a1.z; v1.w += a1.w;
            }
        }
        if (j.amode == 4 && kc == 0) { // += u_{16j} (node base term)
            long ur = (long)(256 * (rr >> 4) + (rr & 15)) * 512;
            float4 a0 = *(const float4*)(j.A + ur + c);
            float4 a1 = *(const float4*)(j.A + ur + c + 4);
            v0.x += a0.x; v0.y += a0.y; v0.z += a0.z; v0.w += a0.w;
            v1.x += a1.x; v1.y += a1.y; v1.z += a1.z; v1.w += a1.w;
        }
        *(float4*)(Cp + coff + (long)rr * 512 + c) = v0;
        *(float4*)(Cp + coff + (long)rr * 512 + c + 4) = v1;
    }
}

struct GPack { GJob j[3]; int n0, n1; };

__global__ __launch_bounds__(256) void gpack(GPack p) {
    __shared__ float sm[GSM2];
    int b = blockIdx.x, rel;
    const GJob* jb;
    if (b < p.n0) { jb = &p.j[0]; rel = b; }
    else if (b < p.n0 + p.n1) { jb = &p.j[1]; rel = b - p.n0; }
    else { jb = &p.j[2]; rel = b - p.n0 - p.n1; }
    if (jb->amode == 8) {              // slot0 init: copy A, zero slabs 1..3
        const float4* src = (const float4*)jb->A;
        float4* dst = (float4*)jb->C;
        for (int i = rel * 256 + threadIdx.x; i < SS; i += jb->nbx * 256)
            dst[i] = (i < SS / 4) ? src[i] : make_float4(0.f, 0.f, 0.f, 0.f);
        return;
    }
    if (jb->amode == 9) {              // slab reduce: C = sum_{q<nsA} A[q*ssA]
        const float4* src = (const float4*)jb->A;
        float4* dst = (float4*)jb->C;
        int ss4 = jb->ssA >> 2;
        for (int i = rel * 256 + threadIdx.x; i < jb->M; i += jb->nbx * 256) {
            float4 s = src[i];
            for (int q = 1; q < jb->nsA; ++q) {
                float4 t = src[i + (long)q * ss4];
                s.x += t.x; s.y += t.y; s.z += t.z; s.w += t.w;
            }
            dst[i] = s;
        }
        return;
    }
    g128run(sm, *jb, rel);
}

// ---------------------------------------------------------------------------
// Thin split-K GEMM core: BM=16, BN=64, BK=64, 4 out/thread, slab outputs.
// SUB 0: L3 combine  (A from Wd nodes, B = {A16,A32,A48} 4-slab sums)
// SUB 1: zw = x_last @ Wr
// SUB 2: h1p = zn @ W1        SUB 3: op = relu(b1 + sum4 h1p) @ W2
// ---------------------------------------------------------------------------
struct TArgs {
    const float* Wd; const float* S15; const float* P32s; const float* P48s;
    const float* x; const float* Wr; const float* zn; const float* W1;
    const float* h1p; const float* b1; const float* W2;
    const float* P64s; float* P64d;
    float* zq; float* zw; float* h1po; float* op;
};

template <int SUB>
__device__ __forceinline__ float4 tA(const TArgs& ta, int rg, int b, int gk) {
    if (SUB == 0) {
        int seg = gk >> 9;
        return *(const float4*)(ta.Wd + (long)((4 * rg + seg + 1) * 16 + b) * 512 +
                                (gk & 511));
    } else if (SUB == 1) {
        return *(const float4*)(ta.x + ((long)b * T_ + T_ - 1) * L_ + gk);
    } else if (SUB == 2) {
        return *(const float4*)(ta.zn + (long)b * 512 + gk);
    } else {
        float4 s = *(const float4*)(ta.b1 + gk);
#pragma unroll
        for (int q = 0; q < 4; ++q) {
            float4 h = *(const float4*)(ta.h1p + (long)q * 16 * F_ + (long)b * F_ + gk);
            s.x += h.x; s.y += h.y; s.z += h.z; s.w += h.w;
        }
        return make_float4(fmaxf(s.x, 0.f), fmaxf(s.y, 0.f),
                           fmaxf(s.z, 0.f), fmaxf(s.w, 0.f));
    }
}

template <int SUB>
__device__ __forceinline__ float4 tB(const TArgs& ta, int gk, int c) {
    if (SUB == 0) {
        int seg = gk >> 9;
        const float* base = (seg == 0) ? ta.S15 : (seg == 1) ? ta.P32s : ta.P48s;
        const float* p = base + (long)(gk & 511) * 512 + c;
        float4 s = *(const float4*)p;
#pragma unroll
        for (int q = 1; q < 4; ++q) {
            float4 t = *(const float4*)(p + (long)q * SS);
            s.x += t.x; s.y += t.y; s.z += t.z; s.w += t.w;
        }
        return s;
    } else if (SUB == 1) {
        return *(const float4*)(ta.Wr + (long)gk * 512 + c);
    } else if (SUB == 2) {
        return *(const float4*)(ta.W1 + (long)gk * F_ + c);
    } else {
        return *(const float4*)(ta.W2 + (long)gk * 512 + c);
    }
}

template <int SUB>
__device__ __forceinline__ void thin_core(float* sm, const TArgs& ta,
                                          int bx, int rg, int kc, int kLen) {
    constexpr int LDC = (SUB == 2) ? F_ : H_;
    float* As = sm;                  // [64][20]
    float* Bs = sm + 64 * 20;        // [64][68]
    const int tid = threadIdx.x, tx = tid & 15, ty = tid >> 4;
    const int col0 = bx * 64, kOff = kc * kLen;

    float4 pa, pb[4];
    pa = tA<SUB>(ta, rg, ty, kOff + tx * 4);
#pragma unroll
    for (int t = 0; t < 4; ++t) {
        int f = tid + t * 256;
        pb[t] = tB<SUB>(ta, kOff + (f >> 4), col0 + (f & 15) * 4);
    }
    float acc[4] = {};
    for (int k0 = 0; k0 < kLen; k0 += 64) {
        __syncthreads();
        {
            int kk = tx * 4;
            As[(kk + 0) * 20 + ty] = pa.x;
            As[(kk + 1) * 20 + ty] = pa.y;
            As[(kk + 2) * 20 + ty] = pa.z;
            As[(kk + 3) * 20 + ty] = pa.w;
        }
#pragma unroll
        for (int t = 0; t < 4; ++t) {
            int f = tid + t * 256;
            *(float4*)&Bs[(f >> 4) * 68 + (f & 15) * 4] = pb[t];
        }
        __syncthreads();
        int kn = k0 + 64;
        if (kn < kLen) {
            pa = tA<SUB>(ta, rg, ty, kOff + kn + tx * 4);
#pragma unroll
            for (int t = 0; t < 4; ++t) {
                int f = tid + t * 256;
                pb[t] = tB<SUB>(ta, kOff + kn + (f >> 4), col0 + (f & 15) * 4);
            }
        }
#pragma unroll
        for (int kk = 0; kk < 64; ++kk) {
            float ra = As[kk * 20 + ty];
            float4 rb = *(float4*)&Bs[kk * 68 + tx * 4];
            acc[0] = fmaf(ra, rb.x, acc[0]);
            acc[1] = fmaf(ra, rb.y, acc[1]);
            acc[2] = fmaf(ra, rb.z, acc[2]);
            acc[3] = fmaf(ra, rb.w, acc[3]);
        }
    }
    float4 v = make_float4(acc[0], acc[1], acc[2], acc[3]);
    float* dst;
    if (SUB == 0) {
        if (kc == 0) {                 // += w_{4s} base node
            float4 a = *(const float4*)(ta.Wd + (long)(64 * rg + ty) * 512 +
                                        col0 + tx * 4);
            v.x += a.x; v.y += a.y; v.z += a.z; v.w += a.w;
        }
        dst = ta.zq + (long)kc * 32 * 512 + (long)(rg * 16 + ty) * 512 + col0 + tx * 4;
    } else if (SUB == 1) {
        dst = ta.zw + (long)ty * 512 + col0 + tx * 4;
    } else if (SUB == 2) {
        dst = ta.h1po + (long)kc * 16 * F_ + (long)ty * F_ + col0 + tx * 4;
    } else {
        dst = ta.op + (long)kc * 16 * 512 + (long)ty * 512 + col0 + tx * 4;
    }
    *(float4*)dst = v;
}

// K6: L3 (48) + ZW (8) + P64 reduce (32)
__global__ __launch_bounds__(256) void t6(TArgs ta) {
    __shared__ float sm[64 * 20 + 64 * 68];
    int b = blockIdx.x;
    if (b < 48) {
        int bx = b % 8, r = b / 8;
        thin_core<0>(sm, ta, bx, r % 2, r / 2, 512);
    } else if (b < 56) {
        thin_core<1>(sm, ta, b - 48, 0, 0, 128);
    } else {
        const float4* src = (const float4*)ta.P64s;
        float4* dst = (float4*)ta.P64d;
        for (int i = (b - 56) * 256 + threadIdx.x; i < SS / 4; i += 32 * 256) {
            float4 s = src[i];
#pragma unroll
            for (int q = 1; q < 4; ++q) {
                float4 t = src[i + (long)q * (SS / 4)];
                s.x += t.x; s.y += t.y; s.z += t.z; s.w += t.w;
            }
            dst[i] = s;
        }
    }
}

template <int SUB>
__global__ __launch_bounds__(256) void tm(TArgs ta, int nbx, int kLen) {
    __shared__ float sm[64 * 20 + 64 * 68];
    thin_core<SUB>(sm, ta, blockIdx.x % nbx, 0, blockIdx.x / nbx, kLen);
}

// ---------------------------------------------------------------------------
// zln: h = t0 + t1@A64 ; z = h + zw + br ; LayerNorm -> zn.  grid=16
// ---------------------------------------------------------------------------
__global__ __launch_bounds__(256) void zln(
    const float* __restrict__ zq, const float* __restrict__ zw,
    const float* __restrict__ P64d, const float* __restrict__ br,
    const float* __restrict__ lng, const float* __restrict__ lnb,
    float* __restrict__ zn)
{
    __shared__ float t1row[512];
    __shared__ float red1[4], red2[4];
    const int b = blockIdx.x, tid = threadIdx.x;
    for (int i = tid; i < 512; i += 256) {
        float s = 0.f;
#pragma unroll
        for (int q = 0; q < 3; ++q)
            s += zq[(long)q * 32 * 512 + (long)(16 + b) * 512 + i];
        t1row[i] = s;
    }
    __syncthreads();
    int c0 = tid, c1 = tid + 256;
    float z0 = br[c0] + zw[(long)b * 512 + c0];
    float z1 = br[c1] + zw[(long)b * 512 + c1];
#pragma unroll
    for (int q = 0; q < 3; ++q) {
        z0 += zq[(long)q * 32 * 512 + (long)b * 512 + c0];
        z1 += zq[(long)q * 32 * 512 + (long)b * 512 + c1];
    }
    for (int k = 0; k < 512; k += 4) {
#pragma unroll
        for (int u = 0; u < 4; ++u) {
            float t = t1row[k + u];
            z0 = fmaf(t, P64d[(long)(k + u) * 512 + c0], z0);
            z1 = fmaf(t, P64d[(long)(k + u) * 512 + c1], z1);
        }
    }
    float s1 = z0 + z1;
    float s2 = z0 * z0 + z1 * z1;
#pragma unroll
    for (int off = 32; off > 0; off >>= 1) {
        s1 += __shfl_down(s1, off, 64);
        s2 += __shfl_down(s2, off, 64);
    }
    int wid = tid >> 6, lane = tid & 63;
    if (lane == 0) { red1[wid] = s1; red2[wid] = s2; }
    __syncthreads();
    float S1 = red1[0] + red1[1] + red1[2] + red1[3];
    float S2 = red2[0] + red2[1] + red2[2] + red2[3];
    float mu  = S1 * (1.0f / H_);
    float var = S2 * (1.0f / H_) - mu * mu;
    float rs  = rsqrtf(var + EPS);
    zn[(long)b * 512 + c0] = (z0 - mu) * rs * lng[c0] + lnb[c0];
    zn[(long)b * 512 + c1] = (z1 - mu) * rs * lng[c1] + lnb[c1];
}

// out = b2 + sum8 op.  grid=32
__global__ __launch_bounds__(256) void ored(
    const float* __restrict__ op, const float* __restrict__ b2,
    float* __restrict__ out)
{
    int b = blockIdx.x >> 1;
    int c = (blockIdx.x & 1) * 256 + threadIdx.x;
    float s = b2[c];
#pragma unroll
    for (int q = 0; q < 8; ++q) s += op[(long)q * 16 * 512 + (long)b * 512 + c];
    out[(long)b * 512 + c] = s;
}

// ---------------------------------------------------------------------------
extern "C" void kernel_launch(void* const* d_in, const int* in_sizes, int n_in,
                              void* d_out, int out_size, void* d_ws, size_t ws_size,
                              hipStream_t stream) {
    const float* x    = (const float*)d_in[0];
    const float* We   = (const float*)d_in[1];
    const float* be   = (const float*)d_in[2];
    const float* Wb   = (const float*)d_in[3];
    const float* Amat = (const float*)d_in[4];
    const float* Wr   = (const float*)d_in[5];
    const float* br   = (const float*)d_in[6];
    const float* lng  = (const float*)d_in[7];
    const float* lnb  = (const float*)d_in[8];
    const float* W1   = (const float*)d_in[9];
    const float* b1   = (const float*)d_in[10];
    const float* W2   = (const float*)d_in[11];
    const float* b2   = (const float*)d_in[12];
    float* out = (float*)d_out;

    float* ws   = (float*)d_ws;
    float* Pstk = ws;                        // 16 slots x 4 slabs x SS (A^1..A^16)
    float* P32s = Pstk + (long)16 * 4 * SS;  // 4 slabs
    float* P48s = P32s + 4 * SS;             // 4 slabs
    float* P64s = P48s + 4 * SS;             // 4 slabs
    float* P64d = P64s + 4 * SS;             // dense A^64
    float* Wcs  = P64d + SS;                 // 2 x 129 x 512
    float* U    = Wcs + 2 * 129 * 512;       // 2048 x 512
    float* L1s  = U + 2048 * 512;            // 60 x 128 x 512
    float* Wd   = L1s + (long)60 * 128 * 512;// 128 x 512 (w_0..w_7 nodes)
    float* zq   = Wd + 128 * 512;            // 3 x 32 x 512
    float* zw   = zq + 3 * 32 * 512;         // 16 x 512
    float* zn   = zw + 16 * 512;             // 16 x 512
    float* h1p  = zn + 16 * 512;             // 4 x 16 x 1024
    float* op   = h1p + 4 * 16 * F_;         // 8 x 16 x 512

#define SLOT(i) (Pstk + (long)(i) * 4 * SS)

    // K0: Wc=[We;be]@Wb (16) || A^2 -> slot1 (64) || slot0 init (32)
    {
        GPack p;
        p.j[0] = {We, be, Wb, Wcs, 129, 256, 128, 4, 2, 2, 1, 1, 0, 1, 0, 1, 0, 0, 0};
        p.j[1] = {Amat, nullptr, Amat, SLOT(1), 512, 512, 128, 4, 4, 4, 1, 0, 0, 1, 0, 1, 0, 0, 0};
        p.j[2] = {Amat, nullptr, nullptr, SLOT(0), 0, 0, 0, 32, 0, 0, 0, 8, 0, 1, 0, 1, 0, 0, 0};
        p.n0 = 16; p.n1 = 64;
        gpack<<<112, 256, 0, stream>>>(p);
    }
    // K1: U (64) || A^3 = A^2*A -> slot2 (64) || A^4 = A^2*A^2 -> slot3 (64)
    {
        GPack p;
        p.j[0] = {x, Wcs + 128 * 512, Wcs, U, 2048, 0, 128, 4, 16, 1, 1, 3, 0, 1, 129 * 512, 2, 129 * 512, 0, 0};
        p.j[1] = {SLOT(1), nullptr, Amat, SLOT(2), 512, 512, 128, 4, 4, 4, 1, 0, 0, 4, SS, 1, 0, 0, 0};
        p.j[2] = {SLOT(1), nullptr, SLOT(1), SLOT(3), 512, 512, 128, 4, 4, 4, 1, 0, 0, 4, SS, 4, SS, 0, 0};
        p.n0 = 64; p.n1 = 64;
        gpack<<<192, 256, 0, stream>>>(p);
    }
    // K2: batch4: A^5..A^8 = A^4 * {A..A^4} -> slots 4..7 (256)
    {
        GPack p;
        p.j[0] = {SLOT(3), nullptr, Pstk, SLOT(4), 512, 512, 128, 4, 4, 4, 4, 0, 0, 4, SS, 4, SS, (long)4 * SS, (long)4 * SS};
        p.j[1] = p.j[0]; p.j[2] = p.j[0];
        p.n0 = 256; p.n1 = 0;
        gpack<<<256, 256, 0, stream>>>(p);
    }
    // K3: batch8: A^9..A^16 = A^8 * {A..A^8} -> slots 8..15 (512)
    {
        GPack p;
        p.j[0] = {SLOT(7), nullptr, Pstk, SLOT(8), 512, 512, 128, 4, 4, 4, 8, 0, 0, 4, SS, 4, SS, (long)4 * SS, (long)4 * SS};
        p.j[1] = p.j[0]; p.j[2] = p.j[0];
        p.n0 = 512; p.n1 = 0;
        gpack<<<512, 256, 0, stream>>>(p);
    }
    // K4: L1 combine (240: w_j = sum_i u_{16j+i} A^i, K=7680, 60 slabs)
    //     || A^32 = A^16*A^16 -> P32s (64)
    {
        GPack p;
        p.j[0] = {U, nullptr, Pstk, L1s, 128, 512, 128, 4, 1, 60, 1, 4, 1, 1, 0, 4, SS, 0, 0};
        p.j[1] = {SLOT(15), nullptr, SLOT(15), P32s, 512, 512, 128, 4, 4, 4, 1, 0, 0, 4, SS, 4, SS, 0, 0};
        p.j[2] = p.j[1];
        p.n0 = 240; p.n1 = 64;
        gpack<<<304, 256, 0, stream>>>(p);
    }
    // K5: A^48 = A^16*A^32 (64) || A^64 = A^32*A^32 (64) || L1 reduce -> Wd (32)
    {
        GPack p;
        p.j[0] = {SLOT(15), nullptr, P32s, P48s, 512, 512, 128, 4, 4, 4, 1, 0, 0, 4, SS, 4, SS, 0, 0};
        p.j[1] = {P32s, nullptr, P32s, P64s, 512, 512, 128, 4, 4, 4, 1, 0, 0, 4, SS, 4, SS, 0, 0};
        p.j[2] = {L1s, nullptr, nullptr, Wd, 128 * 512 / 4, 0, 0, 32, 0, 0, 0, 9, 0, 60, 128 * 512, 1, 0, 0, 0};
        p.n0 = 64; p.n1 = 64;
        gpack<<<160, 256, 0, stream>>>(p);
    }
    TArgs ta;
    ta.Wd = Wd; ta.S15 = SLOT(15); ta.P32s = P32s; ta.P48s = P48s;
    ta.x = x; ta.Wr = Wr; ta.zn = zn; ta.W1 = W1; ta.h1p = h1p;
    ta.b1 = b1; ta.W2 = W2; ta.P64s = P64s; ta.P64d = P64d;
    ta.zq = zq; ta.zw = zw; ta.h1po = h1p; ta.op = op;

    // K6: L3 t_s = w_{4s} + sum_m w_{4s+m} A^{16m} (48) || zw (8) || P64red (32)
    t6<<<88, 256, 0, stream>>>(ta);
    // K7: zln (h = t0 + t1@A64; +zw +br; LN)
    zln<<<16, 256, 0, stream>>>(zq, zw, P64d, br, lng, lnb, zn);
    // K8: h1p = zn@W1 (K=512, 4 kc x 16 col = 64)
    tm<2><<<64, 256, 0, stream>>>(ta, 16, 128);
    // K9: op = relu(b1+sum4 h1p)@W2 (K=1024, 8 kc x 8 col = 64)
    tm<3><<<64, 256, 0, stream>>>(ta, 8, 128);
    // K10: out = b2 + sum8 op
    ored<<<32, 256, 0, stream>>>(op, b2, out);
}